// Round 1
// baseline (1199.118 us; speedup 1.0000x reference)
//
#include <hip/hip_runtime.h>
#include <hip/hip_bf16.h>
#include <math.h>

#define B_ 4
#define N_ 8192
#define K_ 16
#define BN_ (B_ * N_)
#define EPS_ 1e-5f
#define QPB 128   // queries per KNN block (2 threads each -> 256 threads)

// ---------------- pack coords (B*N,3) -> float4 ----------------
__global__ __launch_bounds__(256) void pack_coords(const float* __restrict__ coords,
                                                   float4* __restrict__ out) {
    int i = blockIdx.x * 256 + threadIdx.x;
    if (i >= BN_) return;
    out[i] = make_float4(coords[3 * i], coords[3 * i + 1], coords[3 * i + 2], 0.0f);
}

// ---------------- exact 16-NN ----------------
// 2 threads per query, each scans interleaved half of the 8192 candidates,
// keeps a sorted top-16 in registers, then pair-merge via LDS.
__global__ __launch_bounds__(256) void knn_kernel(const float4* __restrict__ coords4,
                                                  int* __restrict__ idxOut) {
    const int bpb = N_ / QPB;                 // blocks per batch = 64
    int b = blockIdx.x / bpb;
    int qbase = (blockIdx.x % bpb) * QPB;
    int t = threadIdx.x;
    int s = t & 1;                            // candidate split
    int ql = t >> 1;                          // local query
    int q = qbase + ql;                       // query index within batch

    const float4* cb = coords4 + (size_t)b * N_;
    float4 qc = cb[q];

    float key[K_];
    int   id[K_];
#pragma unroll
    for (int j = 0; j < K_; j++) { key[j] = 3.4e38f; id[j] = -1; }

#pragma unroll 4
    for (int i = 0; i < N_ / 2; i++) {
        int m = (i << 1) | s;
        float4 c = cb[m];
        float dx = qc.x - c.x, dy = qc.y - c.y, dz = qc.z - c.z;
        float d2 = dx * dx;
        d2 = fmaf(dy, dy, d2);
        d2 = fmaf(dz, dz, d2);
        if (d2 < key[K_ - 1]) {
            // branchless sorted insertion (reads originals: iter j writes only slot j)
#pragma unroll
            for (int j = K_ - 1; j > 0; --j) {
                bool up = d2 < key[j - 1];
                float ik = fminf(d2, key[j]);
                int   ii = (d2 < key[j]) ? m : id[j];
                key[j] = up ? key[j - 1] : ik;
                id[j]  = up ? id[j - 1]  : ii;
            }
            if (d2 < key[0]) { key[0] = d2; id[0] = m; }
        }
    }

    // pairwise merge of the two sorted 16-lists per query
    __shared__ float skey[256][K_ + 1];
    __shared__ int   sid[256][K_ + 1];
#pragma unroll
    for (int j = 0; j < K_; j++) { skey[t][j] = key[j]; sid[t][j] = id[j]; }
    __syncthreads();
    if (s == 0) {
        int ta = t, tb = t + 1;
        int ia = 0, ib = 0;
        int* op = idxOut + ((size_t)b * N_ + q) * K_;
        for (int r = 0; r < K_; r++) {
            float ka = skey[ta][ia], kb = skey[tb][ib];
            if (ka <= kb) { op[r] = sid[ta][ia]; ia++; }
            else          { op[r] = sid[tb][ib]; ib++; }
        }
    }
}

// ---------------- gather 16 neighbor rows of feats, mean ----------------
// one wave per query row: lane = channel (coalesced 256B row reads)
__global__ __launch_bounds__(256) void gather_mean(const float* __restrict__ feats,
                                                   const int* __restrict__ idx,
                                                   float* __restrict__ x0) {
    int t = blockIdx.x * 256 + threadIdx.x;   // over BN_*64
    int row = t >> 6;
    int c = t & 63;
    int b = row >> 13;                        // N_=8192
    const float* fb = feats + ((size_t)b * N_) * 64;
    const int* ip = idx + (size_t)row * K_;
    float acc = 0.0f;
#pragma unroll
    for (int j = 0; j < K_; j++) acc += fb[(size_t)ip[j] * 64 + c];
    x0[(size_t)row * 64 + c] = acc * (1.0f / 16.0f);
}

// ---------------- stage 1: y1 = x0 @ W1 + b1 ----------------
__global__ __launch_bounds__(64) void mm1_kernel(const float* __restrict__ X,
                                                 const float* __restrict__ W,
                                                 const float* __restrict__ bias,
                                                 float* __restrict__ Y) {
    __shared__ float Ws[64 * 64];
    for (int i = threadIdx.x; i < 64 * 64; i += 64) Ws[i] = W[i];
    __syncthreads();
    size_t r = (size_t)blockIdx.x * 64 + threadIdx.x;
    float x[64];
    const float4* xp = (const float4*)(X + r * 64);
#pragma unroll
    for (int i = 0; i < 16; i++) {
        float4 v = xp[i];
        x[4 * i] = v.x; x[4 * i + 1] = v.y; x[4 * i + 2] = v.z; x[4 * i + 3] = v.w;
    }
    float acc[64];
#pragma unroll
    for (int j = 0; j < 64; j++) acc[j] = bias[j];
    for (int c = 0; c < 64; c++) {
        float xv = x[c];
#pragma unroll
        for (int j = 0; j < 64; j++) acc[j] = fmaf(xv, Ws[c * 64 + j], acc[j]);
    }
    float4* yp = (float4*)(Y + r * 64);
#pragma unroll
    for (int i = 0; i < 16; i++)
        yp[i] = make_float4(acc[4 * i], acc[4 * i + 1], acc[4 * i + 2], acc[4 * i + 3]);
}

// ---------------- per-channel sum/sumsq partials (deterministic) ----------------
template <int C>
__global__ __launch_bounds__(256) void stat_partial(const float* __restrict__ Y,
                                                    float* __restrict__ part) {
    const int RP = 256 / C;
    int c = threadIdx.x & (C - 1);
    int rs = threadIdx.x / C;
    float s1 = 0.0f, s2 = 0.0f;
    for (int r = blockIdx.x * RP + rs; r < BN_; r += gridDim.x * RP) {
        float v = Y[(size_t)r * C + c];
        s1 += v;
        s2 = fmaf(v, v, s2);
    }
    __shared__ float l1[256], l2[256];
    l1[threadIdx.x] = s1; l2[threadIdx.x] = s2;
    __syncthreads();
    if (threadIdx.x < C) {
#pragma unroll
        for (int k = 1; k < RP; k++) { s1 += l1[threadIdx.x + k * C]; s2 += l2[threadIdx.x + k * C]; }
        part[(size_t)blockIdx.x * 2 * C + c] = s1;
        part[(size_t)blockIdx.x * 2 * C + C + c] = s2;
    }
}

template <int C>
__global__ void stat_reduce(const float* __restrict__ part, int G, float* __restrict__ stats) {
    int c = threadIdx.x;
    if (c >= C) return;
    float s1 = 0.0f, s2 = 0.0f;
    for (int g = 0; g < G; g++) { s1 += part[(size_t)g * 2 * C + c]; s2 += part[(size_t)g * 2 * C + C + c]; }
    float mean = s1 / (float)BN_;
    float var = s2 / (float)BN_ - mean * mean;
    stats[c] = mean;
    stats[C + c] = rsqrtf(var + EPS_);
}

// ---------------- stage 2: x1 = relu(bn1(y1)); y2 = x1 @ Wa + ba ----------------
__global__ __launch_bounds__(64) void mm2_kernel(const float* __restrict__ Y1,
                                                 const float* __restrict__ Wa,
                                                 const float* __restrict__ ba,
                                                 const float* __restrict__ g1,
                                                 const float* __restrict__ be1,
                                                 const float* __restrict__ stats1,
                                                 float* __restrict__ X1,
                                                 float* __restrict__ Y2) {
    __shared__ float Ws[64 * 64];
    __shared__ float sc[64], sh[64];
    for (int i = threadIdx.x; i < 64 * 64; i += 64) Ws[i] = Wa[i];
    {
        int c = threadIdx.x;
        float m = stats1[c], rs = stats1[64 + c];
        float scale = rs * g1[c];
        sc[c] = scale;
        sh[c] = be1[c] - m * scale;
    }
    __syncthreads();
    size_t r = (size_t)blockIdx.x * 64 + threadIdx.x;
    float x[64];
    const float4* xp = (const float4*)(Y1 + r * 64);
#pragma unroll
    for (int i = 0; i < 16; i++) {
        float4 v = xp[i];
        x[4 * i]     = fmaxf(0.0f, fmaf(v.x, sc[4 * i],     sh[4 * i]));
        x[4 * i + 1] = fmaxf(0.0f, fmaf(v.y, sc[4 * i + 1], sh[4 * i + 1]));
        x[4 * i + 2] = fmaxf(0.0f, fmaf(v.z, sc[4 * i + 2], sh[4 * i + 2]));
        x[4 * i + 3] = fmaxf(0.0f, fmaf(v.w, sc[4 * i + 3], sh[4 * i + 3]));
    }
    float4* x1p = (float4*)(X1 + r * 64);
#pragma unroll
    for (int i = 0; i < 16; i++)
        x1p[i] = make_float4(x[4 * i], x[4 * i + 1], x[4 * i + 2], x[4 * i + 3]);
    float acc[64];
#pragma unroll
    for (int j = 0; j < 64; j++) acc[j] = ba[j];
    for (int c = 0; c < 64; c++) {
        float xv = x[c];
#pragma unroll
        for (int j = 0; j < 64; j++) acc[j] = fmaf(xv, Ws[c * 64 + j], acc[j]);
    }
    float4* yp = (float4*)(Y2 + r * 64);
#pragma unroll
    for (int i = 0; i < 16; i++)
        yp[i] = make_float4(acc[4 * i], acc[4 * i + 1], acc[4 * i + 2], acc[4 * i + 3]);
}

// ---------------- stage 3: attn = sigmoid(relu(bn2(y2))); fused = x1*(1+attn); y3 = fused @ W2 + b2 ----------------
__global__ __launch_bounds__(64) void mm3_kernel(const float* __restrict__ Y2,
                                                 const float* __restrict__ X1,
                                                 const float* __restrict__ W2,
                                                 const float* __restrict__ b2,
                                                 const float* __restrict__ ga,
                                                 const float* __restrict__ bea,
                                                 const float* __restrict__ stats2,
                                                 float* __restrict__ Y3) {
    __shared__ float Ws[64 * 128];
    __shared__ float sc[64], sh[64];
    for (int i = threadIdx.x; i < 64 * 128; i += 64) Ws[i] = W2[i];
    {
        int c = threadIdx.x;
        float m = stats2[c], rs = stats2[64 + c];
        float scale = rs * ga[c];
        sc[c] = scale;
        sh[c] = bea[c] - m * scale;
    }
    __syncthreads();
    size_t r = (size_t)blockIdx.x * 64 + threadIdx.x;
    float fx[64];
    const float4* y2p = (const float4*)(Y2 + r * 64);
    const float4* x1p = (const float4*)(X1 + r * 64);
#pragma unroll
    for (int i = 0; i < 16; i++) {
        float4 v = y2p[i];
        float4 u = x1p[i];
        float t0 = fmaxf(0.0f, fmaf(v.x, sc[4 * i],     sh[4 * i]));
        float t1 = fmaxf(0.0f, fmaf(v.y, sc[4 * i + 1], sh[4 * i + 1]));
        float t2 = fmaxf(0.0f, fmaf(v.z, sc[4 * i + 2], sh[4 * i + 2]));
        float t3 = fmaxf(0.0f, fmaf(v.w, sc[4 * i + 3], sh[4 * i + 3]));
        float a0 = 1.0f / (1.0f + __expf(-t0));
        float a1 = 1.0f / (1.0f + __expf(-t1));
        float a2 = 1.0f / (1.0f + __expf(-t2));
        float a3 = 1.0f / (1.0f + __expf(-t3));
        fx[4 * i]     = u.x * (1.0f + a0);
        fx[4 * i + 1] = u.y * (1.0f + a1);
        fx[4 * i + 2] = u.z * (1.0f + a2);
        fx[4 * i + 3] = u.w * (1.0f + a3);
    }
    float acc[64];
#pragma unroll 1
    for (int h = 0; h < 2; ++h) {
#pragma unroll
        for (int j = 0; j < 64; j++) acc[j] = b2[h * 64 + j];
        for (int c = 0; c < 64; c++) {
            float xv = fx[c];
#pragma unroll
            for (int j = 0; j < 64; j++) acc[j] = fmaf(xv, Ws[c * 128 + h * 64 + j], acc[j]);
        }
        float4* yp = (float4*)(Y3 + r * 128 + h * 64);
#pragma unroll
        for (int i = 0; i < 16; i++)
            yp[i] = make_float4(acc[4 * i], acc[4 * i + 1], acc[4 * i + 2], acc[4 * i + 3]);
    }
}

// ---------------- final: out = relu(bn3(y3)) in-place ----------------
__global__ __launch_bounds__(256) void bn_final(float* __restrict__ Y3,
                                                const float* __restrict__ g2,
                                                const float* __restrict__ be2,
                                                const float* __restrict__ stats3) {
    __shared__ float sc[128], sh[128];
    if (threadIdx.x < 128) {
        int c = threadIdx.x;
        float m = stats3[c], rs = stats3[128 + c];
        float s = rs * g2[c];
        sc[c] = s;
        sh[c] = be2[c] - m * s;
    }
    __syncthreads();
    size_t i = (size_t)blockIdx.x * 256 + threadIdx.x;   // over BN_*128/4 float4s
    float4* p = (float4*)Y3;
    float4 v = p[i];
    int c0 = (int)((i * 4) & 127);
    v.x = fmaxf(0.0f, fmaf(v.x, sc[c0],     sh[c0]));
    v.y = fmaxf(0.0f, fmaf(v.y, sc[c0 + 1], sh[c0 + 1]));
    v.z = fmaxf(0.0f, fmaf(v.z, sc[c0 + 2], sh[c0 + 2]));
    v.w = fmaxf(0.0f, fmaf(v.w, sc[c0 + 3], sh[c0 + 3]));
    p[i] = v;
}

extern "C" void kernel_launch(void* const* d_in, const int* in_sizes, int n_in,
                              void* d_out, int out_size, void* d_ws, size_t ws_size,
                              hipStream_t stream) {
    const float* coords = (const float*)d_in[0];
    const float* feats  = (const float*)d_in[1];
    const float* W1  = (const float*)d_in[3];
    const float* b1  = (const float*)d_in[4];
    const float* g1  = (const float*)d_in[5];
    const float* be1 = (const float*)d_in[6];
    const float* Wa  = (const float*)d_in[7];
    const float* ba  = (const float*)d_in[8];
    const float* ga  = (const float*)d_in[9];
    const float* bea = (const float*)d_in[10];
    const float* W2  = (const float*)d_in[11];
    const float* b2  = (const float*)d_in[12];
    const float* g2  = (const float*)d_in[13];
    const float* be2 = (const float*)d_in[14];

    float* ws = (float*)d_ws;
    float4* coords4 = (float4*)ws;                         // BN_ float4 = 131072 floats
    int*    idxbuf  = (int*)(ws + 131072);                 // BN_*16 ints = 524288 slots
    float*  x0 = ws + 131072 + 524288;                     // BN_*64
    float*  y1 = x0 + (size_t)BN_ * 64;
    float*  x1 = y1 + (size_t)BN_ * 64;
    float*  y2 = x1 + (size_t)BN_ * 64;
    float*  part   = y2 + (size_t)BN_ * 64;                // 256 * 256 floats
    float*  stats1 = part + 256 * 256;                     // 128
    float*  stats2 = stats1 + 128;                         // 128
    float*  stats3 = stats2 + 128;                         // 256
    float*  y3 = (float*)d_out;                            // BN_*128 lives in d_out

    pack_coords<<<(BN_ + 255) / 256, 256, 0, stream>>>(coords, coords4);
    knn_kernel<<<B_ * (N_ / QPB), 256, 0, stream>>>(coords4, idxbuf);
    gather_mean<<<BN_ * 64 / 256, 256, 0, stream>>>(feats, idxbuf, x0);

    mm1_kernel<<<BN_ / 64, 64, 0, stream>>>(x0, W1, b1, y1);
    stat_partial<64><<<256, 256, 0, stream>>>(y1, part);
    stat_reduce<64><<<1, 64, 0, stream>>>(part, 256, stats1);

    mm2_kernel<<<BN_ / 64, 64, 0, stream>>>(y1, Wa, ba, g1, be1, stats1, x1, y2);
    stat_partial<64><<<256, 256, 0, stream>>>(y2, part);
    stat_reduce<64><<<1, 64, 0, stream>>>(part, 256, stats2);

    mm3_kernel<<<BN_ / 64, 64, 0, stream>>>(y2, x1, W2, b2, ga, bea, stats2, y3);
    stat_partial<128><<<256, 256, 0, stream>>>(y3, part);
    stat_reduce<128><<<1, 128, 0, stream>>>(part, 256, stats3);

    bn_final<<<(size_t)BN_ * 128 / 4 / 256, 256, 0, stream>>>(y3, g2, be2, stats3);
}

// Round 2
// 720.960 us; speedup vs baseline: 1.6632x; 1.6632x over previous
//
#include <hip/hip_runtime.h>
#include <hip/hip_bf16.h>
#include <math.h>

#define B_ 4
#define N_ 8192
#define K_ 16
#define BN_ (B_ * N_)
#define EPS_ 1e-5f

#define S_ 8      // splits (lanes) per query
#define QPB 32    // queries per block (QPB * S_ = 256 threads)
#define DEPTH 16  // deferred-insert buffer depth per lane

// ---------------- pack coords (B*N,3) -> float4 ----------------
__global__ __launch_bounds__(256) void pack_coords(const float* __restrict__ coords,
                                                   float4* __restrict__ out) {
    int i = blockIdx.x * 256 + threadIdx.x;
    if (i >= BN_) return;
    out[i] = make_float4(coords[3 * i], coords[3 * i + 1], coords[3 * i + 2], 0.0f);
}

// ---------------- exact 16-NN, deferred buffered insertion ----------------
// 8 lanes per query; each lane scans 1024 candidates (stride-8 interleave),
// pushes candidates passing its current 16th-distance into an LDS buffer;
// the 16-deep register insertion runs only at (rare) buffer flushes.
// Then a 3-round in-wave tree merge combines the 8 sorted lists.
__global__ __launch_bounds__(256) void knn_kernel(const float4* __restrict__ coords4,
                                                  int* __restrict__ idxOut) {
    __shared__ float bufd[DEPTH][256];
    __shared__ int   bufi[DEPTH][256];

    const int bpb = N_ / QPB;                 // blocks per batch = 256
    int b = blockIdx.x / bpb;
    int qbase = (blockIdx.x % bpb) * QPB;
    int t = threadIdx.x;
    int s = t & (S_ - 1);                     // split id within query
    int ql = t >> 3;                          // local query
    int q = qbase + ql;

    const float4* cb = coords4 + (size_t)b * N_;
    float4 qc = cb[q];

    float key[K_];
    int   id[K_];
#pragma unroll
    for (int j = 0; j < K_; j++) { key[j] = 3.4e38f; id[j] = -1; }

    int cnt = 0;

    auto flush = [&]() {
        for (int j = 0; j < cnt; ++j) {
            float d2 = bufd[j][t];
            int   m  = bufi[j][t];
            if (d2 < key[K_ - 1]) {
#pragma unroll
                for (int jj = K_ - 1; jj > 0; --jj) {
                    bool up = d2 < key[jj - 1];
                    float ik = fminf(d2, key[jj]);
                    int   ii = (d2 < key[jj]) ? m : id[jj];
                    key[jj] = up ? key[jj - 1] : ik;
                    id[jj]  = up ? id[jj - 1]  : ii;
                }
                if (d2 < key[0]) { key[0] = d2; id[0] = m; }
            }
        }
        cnt = 0;
    };

    const int M = N_ / S_;                    // 1024 candidates per lane
    for (int i = 0; i < M; ++i) {
        int m = (i << 3) | s;
        float4 c = cb[m];
        float dx = qc.x - c.x, dy = qc.y - c.y, dz = qc.z - c.z;
        float d2 = dx * dx;
        d2 = fmaf(dy, dy, d2);
        d2 = fmaf(dz, dz, d2);
        if (d2 < key[K_ - 1]) {
            bufd[cnt][t] = d2;
            bufi[cnt][t] = m;
            cnt++;
        }
        if (__any(cnt == DEPTH)) flush();
    }
    flush();

    // publish this lane's sorted 16-list into its LDS column
#pragma unroll
    for (int j = 0; j < K_; j++) { bufd[j][t] = key[j]; bufi[j][t] = id[j]; }

    // tree merge: 8 lists -> 4 -> 2 -> 1 (partners are lanes in the same wave)
    int* op = idxOut + ((size_t)b * N_ + q) * K_;
    for (int step = 1; step < S_; step <<= 1) {
        bool active = (s & (2 * step - 1)) == 0;
        float md[K_];
        int   mi[K_];
        __syncthreads();
        if (active) {
            int pa = t, pb = t + step;
            int ia = 0, ib = 0;
#pragma unroll
            for (int r = 0; r < K_; ++r) {
                float ka = bufd[ia][pa];
                float kb = bufd[ib][pb];
                bool sel = ka <= kb;
                md[r] = sel ? ka : kb;
                mi[r] = sel ? bufi[ia][pa] : bufi[ib][pb];
                ia += sel ? 1 : 0;
                ib += sel ? 0 : 1;
            }
        }
        __syncthreads();
        if (active) {
            if (step == S_ / 2) {
#pragma unroll
                for (int r = 0; r < K_; ++r) op[r] = mi[r];
            } else {
#pragma unroll
                for (int r = 0; r < K_; ++r) { bufd[r][t] = md[r]; bufi[r][t] = mi[r]; }
            }
        }
    }
}

// ---------------- gather 16 neighbor rows of feats, mean ----------------
__global__ __launch_bounds__(256) void gather_mean(const float* __restrict__ feats,
                                                   const int* __restrict__ idx,
                                                   float* __restrict__ x0) {
    int t = blockIdx.x * 256 + threadIdx.x;   // over BN_*64
    int row = t >> 6;
    int c = t & 63;
    int b = row >> 13;                        // N_=8192
    const float* fb = feats + ((size_t)b * N_) * 64;
    const int* ip = idx + (size_t)row * K_;
    float acc = 0.0f;
#pragma unroll
    for (int j = 0; j < K_; j++) acc += fb[(size_t)ip[j] * 64 + c];
    x0[(size_t)row * 64 + c] = acc * (1.0f / 16.0f);
}

// ---------------- stage 1: y1 = x0 @ W1 + b1 ----------------
__global__ __launch_bounds__(64) void mm1_kernel(const float* __restrict__ X,
                                                 const float* __restrict__ W,
                                                 const float* __restrict__ bias,
                                                 float* __restrict__ Y) {
    __shared__ float Ws[64 * 64];
    for (int i = threadIdx.x; i < 64 * 64; i += 64) Ws[i] = W[i];
    __syncthreads();
    size_t r = (size_t)blockIdx.x * 64 + threadIdx.x;
    float x[64];
    const float4* xp = (const float4*)(X + r * 64);
#pragma unroll
    for (int i = 0; i < 16; i++) {
        float4 v = xp[i];
        x[4 * i] = v.x; x[4 * i + 1] = v.y; x[4 * i + 2] = v.z; x[4 * i + 3] = v.w;
    }
    float acc[64];
#pragma unroll
    for (int j = 0; j < 64; j++) acc[j] = bias[j];
    for (int c = 0; c < 64; c++) {
        float xv = x[c];
#pragma unroll
        for (int j = 0; j < 64; j++) acc[j] = fmaf(xv, Ws[c * 64 + j], acc[j]);
    }
    float4* yp = (float4*)(Y + r * 64);
#pragma unroll
    for (int i = 0; i < 16; i++)
        yp[i] = make_float4(acc[4 * i], acc[4 * i + 1], acc[4 * i + 2], acc[4 * i + 3]);
}

// ---------------- per-channel sum/sumsq partials (deterministic) ----------------
template <int C>
__global__ __launch_bounds__(256) void stat_partial(const float* __restrict__ Y,
                                                    float* __restrict__ part) {
    const int RP = 256 / C;
    int c = threadIdx.x & (C - 1);
    int rs = threadIdx.x / C;
    float s1 = 0.0f, s2 = 0.0f;
    for (int r = blockIdx.x * RP + rs; r < BN_; r += gridDim.x * RP) {
        float v = Y[(size_t)r * C + c];
        s1 += v;
        s2 = fmaf(v, v, s2);
    }
    __shared__ float l1[256], l2[256];
    l1[threadIdx.x] = s1; l2[threadIdx.x] = s2;
    __syncthreads();
    if (threadIdx.x < C) {
#pragma unroll
        for (int k = 1; k < RP; k++) { s1 += l1[threadIdx.x + k * C]; s2 += l2[threadIdx.x + k * C]; }
        part[(size_t)blockIdx.x * 2 * C + c] = s1;
        part[(size_t)blockIdx.x * 2 * C + C + c] = s2;
    }
}

template <int C>
__global__ void stat_reduce(const float* __restrict__ part, int G, float* __restrict__ stats) {
    int c = threadIdx.x;
    if (c >= C) return;
    float s1 = 0.0f, s2 = 0.0f;
    for (int g = 0; g < G; g++) { s1 += part[(size_t)g * 2 * C + c]; s2 += part[(size_t)g * 2 * C + C + c]; }
    float mean = s1 / (float)BN_;
    float var = s2 / (float)BN_ - mean * mean;
    stats[c] = mean;
    stats[C + c] = rsqrtf(var + EPS_);
}

// ---------------- stage 2: x1 = relu(bn1(y1)); y2 = x1 @ Wa + ba ----------------
__global__ __launch_bounds__(64) void mm2_kernel(const float* __restrict__ Y1,
                                                 const float* __restrict__ Wa,
                                                 const float* __restrict__ ba,
                                                 const float* __restrict__ g1,
                                                 const float* __restrict__ be1,
                                                 const float* __restrict__ stats1,
                                                 float* __restrict__ X1,
                                                 float* __restrict__ Y2) {
    __shared__ float Ws[64 * 64];
    __shared__ float sc[64], sh[64];
    for (int i = threadIdx.x; i < 64 * 64; i += 64) Ws[i] = Wa[i];
    {
        int c = threadIdx.x;
        float m = stats1[c], rs = stats1[64 + c];
        float scale = rs * g1[c];
        sc[c] = scale;
        sh[c] = be1[c] - m * scale;
    }
    __syncthreads();
    size_t r = (size_t)blockIdx.x * 64 + threadIdx.x;
    float x[64];
    const float4* xp = (const float4*)(Y1 + r * 64);
#pragma unroll
    for (int i = 0; i < 16; i++) {
        float4 v = xp[i];
        x[4 * i]     = fmaxf(0.0f, fmaf(v.x, sc[4 * i],     sh[4 * i]));
        x[4 * i + 1] = fmaxf(0.0f, fmaf(v.y, sc[4 * i + 1], sh[4 * i + 1]));
        x[4 * i + 2] = fmaxf(0.0f, fmaf(v.z, sc[4 * i + 2], sh[4 * i + 2]));
        x[4 * i + 3] = fmaxf(0.0f, fmaf(v.w, sc[4 * i + 3], sh[4 * i + 3]));
    }
    float4* x1p = (float4*)(X1 + r * 64);
#pragma unroll
    for (int i = 0; i < 16; i++)
        x1p[i] = make_float4(x[4 * i], x[4 * i + 1], x[4 * i + 2], x[4 * i + 3]);
    float acc[64];
#pragma unroll
    for (int j = 0; j < 64; j++) acc[j] = ba[j];
    for (int c = 0; c < 64; c++) {
        float xv = x[c];
#pragma unroll
        for (int j = 0; j < 64; j++) acc[j] = fmaf(xv, Ws[c * 64 + j], acc[j]);
    }
    float4* yp = (float4*)(Y2 + r * 64);
#pragma unroll
    for (int i = 0; i < 16; i++)
        yp[i] = make_float4(acc[4 * i], acc[4 * i + 1], acc[4 * i + 2], acc[4 * i + 3]);
}

// ---------------- stage 3: attn = sigmoid(relu(bn2(y2))); fused = x1*(1+attn); y3 = fused @ W2 + b2 ----------------
__global__ __launch_bounds__(64) void mm3_kernel(const float* __restrict__ Y2,
                                                 const float* __restrict__ X1,
                                                 const float* __restrict__ W2,
                                                 const float* __restrict__ b2,
                                                 const float* __restrict__ ga,
                                                 const float* __restrict__ bea,
                                                 const float* __restrict__ stats2,
                                                 float* __restrict__ Y3) {
    __shared__ float Ws[64 * 128];
    __shared__ float sc[64], sh[64];
    for (int i = threadIdx.x; i < 64 * 128; i += 64) Ws[i] = W2[i];
    {
        int c = threadIdx.x;
        float m = stats2[c], rs = stats2[64 + c];
        float scale = rs * ga[c];
        sc[c] = scale;
        sh[c] = bea[c] - m * scale;
    }
    __syncthreads();
    size_t r = (size_t)blockIdx.x * 64 + threadIdx.x;
    float fx[64];
    const float4* y2p = (const float4*)(Y2 + r * 64);
    const float4* x1p = (const float4*)(X1 + r * 64);
#pragma unroll
    for (int i = 0; i < 16; i++) {
        float4 v = y2p[i];
        float4 u = x1p[i];
        float t0 = fmaxf(0.0f, fmaf(v.x, sc[4 * i],     sh[4 * i]));
        float t1 = fmaxf(0.0f, fmaf(v.y, sc[4 * i + 1], sh[4 * i + 1]));
        float t2 = fmaxf(0.0f, fmaf(v.z, sc[4 * i + 2], sh[4 * i + 2]));
        float t3 = fmaxf(0.0f, fmaf(v.w, sc[4 * i + 3], sh[4 * i + 3]));
        float a0 = 1.0f / (1.0f + __expf(-t0));
        float a1 = 1.0f / (1.0f + __expf(-t1));
        float a2 = 1.0f / (1.0f + __expf(-t2));
        float a3 = 1.0f / (1.0f + __expf(-t3));
        fx[4 * i]     = u.x * (1.0f + a0);
        fx[4 * i + 1] = u.y * (1.0f + a1);
        fx[4 * i + 2] = u.z * (1.0f + a2);
        fx[4 * i + 3] = u.w * (1.0f + a3);
    }
    float acc[64];
#pragma unroll 1
    for (int h = 0; h < 2; ++h) {
#pragma unroll
        for (int j = 0; j < 64; j++) acc[j] = b2[h * 64 + j];
        for (int c = 0; c < 64; c++) {
            float xv = fx[c];
#pragma unroll
            for (int j = 0; j < 64; j++) acc[j] = fmaf(xv, Ws[c * 128 + h * 64 + j], acc[j]);
        }
        float4* yp = (float4*)(Y3 + r * 128 + h * 64);
#pragma unroll
        for (int i = 0; i < 16; i++)
            yp[i] = make_float4(acc[4 * i], acc[4 * i + 1], acc[4 * i + 2], acc[4 * i + 3]);
    }
}

// ---------------- final: out = relu(bn3(y3)) in-place ----------------
__global__ __launch_bounds__(256) void bn_final(float* __restrict__ Y3,
                                                const float* __restrict__ g2,
                                                const float* __restrict__ be2,
                                                const float* __restrict__ stats3) {
    __shared__ float sc[128], sh[128];
    if (threadIdx.x < 128) {
        int c = threadIdx.x;
        float m = stats3[c], rs = stats3[128 + c];
        float s = rs * g2[c];
        sc[c] = s;
        sh[c] = be2[c] - m * s;
    }
    __syncthreads();
    size_t i = (size_t)blockIdx.x * 256 + threadIdx.x;   // over BN_*128/4 float4s
    float4* p = (float4*)Y3;
    float4 v = p[i];
    int c0 = (int)((i * 4) & 127);
    v.x = fmaxf(0.0f, fmaf(v.x, sc[c0],     sh[c0]));
    v.y = fmaxf(0.0f, fmaf(v.y, sc[c0 + 1], sh[c0 + 1]));
    v.z = fmaxf(0.0f, fmaf(v.z, sc[c0 + 2], sh[c0 + 2]));
    v.w = fmaxf(0.0f, fmaf(v.w, sc[c0 + 3], sh[c0 + 3]));
    p[i] = v;
}

extern "C" void kernel_launch(void* const* d_in, const int* in_sizes, int n_in,
                              void* d_out, int out_size, void* d_ws, size_t ws_size,
                              hipStream_t stream) {
    const float* coords = (const float*)d_in[0];
    const float* feats  = (const float*)d_in[1];
    const float* W1  = (const float*)d_in[3];
    const float* b1  = (const float*)d_in[4];
    const float* g1  = (const float*)d_in[5];
    const float* be1 = (const float*)d_in[6];
    const float* Wa  = (const float*)d_in[7];
    const float* ba  = (const float*)d_in[8];
    const float* ga  = (const float*)d_in[9];
    const float* bea = (const float*)d_in[10];
    const float* W2  = (const float*)d_in[11];
    const float* b2  = (const float*)d_in[12];
    const float* g2  = (const float*)d_in[13];
    const float* be2 = (const float*)d_in[14];

    float* ws = (float*)d_ws;
    float4* coords4 = (float4*)ws;                         // BN_ float4 = 131072 floats
    int*    idxbuf  = (int*)(ws + 131072);                 // BN_*16 ints = 524288 slots
    float*  x0 = ws + 131072 + 524288;                     // BN_*64
    float*  y1 = x0 + (size_t)BN_ * 64;
    float*  x1 = y1 + (size_t)BN_ * 64;
    float*  y2 = x1 + (size_t)BN_ * 64;
    float*  part   = y2 + (size_t)BN_ * 64;                // 256 * 256 floats
    float*  stats1 = part + 256 * 256;                     // 128
    float*  stats2 = stats1 + 128;                         // 128
    float*  stats3 = stats2 + 128;                         // 256
    float*  y3 = (float*)d_out;                            // BN_*128 lives in d_out

    pack_coords<<<(BN_ + 255) / 256, 256, 0, stream>>>(coords, coords4);
    knn_kernel<<<B_ * (N_ / QPB), 256, 0, stream>>>(coords4, idxbuf);
    gather_mean<<<BN_ * 64 / 256, 256, 0, stream>>>(feats, idxbuf, x0);

    mm1_kernel<<<BN_ / 64, 64, 0, stream>>>(x0, W1, b1, y1);
    stat_partial<64><<<256, 256, 0, stream>>>(y1, part);
    stat_reduce<64><<<1, 64, 0, stream>>>(part, 256, stats1);

    mm2_kernel<<<BN_ / 64, 64, 0, stream>>>(y1, Wa, ba, g1, be1, stats1, x1, y2);
    stat_partial<64><<<256, 256, 0, stream>>>(y2, part);
    stat_reduce<64><<<1, 64, 0, stream>>>(part, 256, stats2);

    mm3_kernel<<<BN_ / 64, 64, 0, stream>>>(y2, x1, W2, b2, ga, bea, stats2, y3);
    stat_partial<128><<<256, 256, 0, stream>>>(y3, part);
    stat_reduce<128><<<1, 128, 0, stream>>>(part, 256, stats3);

    bn_final<<<(size_t)BN_ * 128 / 4 / 256, 256, 0, stream>>>(y3, g2, be2, stats3);
}

// Round 3
// 646.795 us; speedup vs baseline: 1.8539x; 1.1147x over previous
//
#include <hip/hip_runtime.h>
#include <hip/hip_bf16.h>
#include <math.h>

#define B_ 4
#define N_ 8192
#define K_ 16
#define BN_ (B_ * N_)
#define EPS_ 1e-5f

#define S_ 8              // candidate splits = waves per block
#define TPB (S_ * 64)     // 512 threads
#define QPB 64            // queries per block (one per lane)
#define MCAND (N_ / S_)   // 1024 candidates per wave
#define DEPTH 16          // deferred-insert buffer depth per lane

// ---------------- pack coords (B*N,3) -> float4 ----------------
__global__ __launch_bounds__(256) void pack_coords(const float* __restrict__ coords,
                                                   float4* __restrict__ out) {
    int i = blockIdx.x * 256 + threadIdx.x;
    if (i >= BN_) return;
    out[i] = make_float4(coords[3 * i], coords[3 * i + 1], coords[3 * i + 2], 0.0f);
}

// ---------------- exact 16-NN: scalar-broadcast candidates, deferred insertion ----------------
// One query per lane; wave w scans contiguous candidate range [w*1024,(w+1)*1024)
// with wave-uniform addresses (s_load broadcast). Passing candidates go to a
// per-lane LDS buffer; 16-deep register insertion runs only on (rare) flushes.
// 8 sorted lists per query merged via 3-round LDS tree merge.
__global__ __launch_bounds__(512) void knn_kernel(const float4* __restrict__ coords4,
                                                  int* __restrict__ idxOut) {
    __shared__ float bufd[DEPTH][TPB];
    __shared__ int   bufi[DEPTH][TPB];

    const int bpb = N_ / QPB;                 // 128 blocks per batch
    int b = blockIdx.x / bpb;
    int qbase = (blockIdx.x % bpb) * QPB;
    int t = threadIdx.x;
    int lane = t & 63;
    int w = __builtin_amdgcn_readfirstlane(t >> 6);   // wave-uniform split id -> SGPR
    int q = qbase + lane;

    const float4* cb = coords4 + (size_t)b * N_;
    float4 qc = cb[q];
    float qx = qc.x, qy = qc.y, qz = qc.z;

    float key[K_];
    int   id[K_];
#pragma unroll
    for (int j = 0; j < K_; j++) { key[j] = 3.4e38f; id[j] = -1; }

    int cnt = 0;

    auto flush = [&]() {
        for (int j = 0; j < cnt; ++j) {
            float d2 = bufd[j][t];
            int   m  = bufi[j][t];
            if (d2 < key[K_ - 1]) {
#pragma unroll
                for (int jj = K_ - 1; jj > 0; --jj) {
                    bool up = d2 < key[jj - 1];
                    float ik = fminf(d2, key[jj]);
                    int   ii = (d2 < key[jj]) ? m : id[jj];
                    key[jj] = up ? key[jj - 1] : ik;
                    id[jj]  = up ? id[jj - 1]  : ii;
                }
                if (d2 < key[0]) { key[0] = d2; id[0] = m; }
            }
        }
        cnt = 0;
    };

    auto proc = [&](float4 c, int m) {
        float dx = qx - c.x, dy = qy - c.y, dz = qz - c.z;
        float d2 = dx * dx;
        d2 = fmaf(dy, dy, d2);
        d2 = fmaf(dz, dz, d2);
        if (d2 < key[K_ - 1]) {
            bufd[cnt][t] = d2;
            bufi[cnt][t] = m;
            cnt++;
        }
    };

    const int base = w * MCAND;
    for (int i = 0; i < MCAND; i += 8) {
        // wave-uniform addresses -> scalar loads (SMEM broadcast)
        float4 c0 = cb[base + i + 0];
        float4 c1 = cb[base + i + 1];
        float4 c2 = cb[base + i + 2];
        float4 c3 = cb[base + i + 3];
        float4 c4 = cb[base + i + 4];
        float4 c5 = cb[base + i + 5];
        float4 c6 = cb[base + i + 6];
        float4 c7 = cb[base + i + 7];
        proc(c0, base + i + 0);
        proc(c1, base + i + 1);
        proc(c2, base + i + 2);
        proc(c3, base + i + 3);
        proc(c4, base + i + 4);
        proc(c5, base + i + 5);
        proc(c6, base + i + 6);
        proc(c7, base + i + 7);
        // each lane pushed at most 8 since last check; DEPTH-7 guard => no overflow
        if (__any(cnt >= DEPTH - 7)) flush();
    }
    flush();

    // publish this lane's sorted 16-list into its LDS column
#pragma unroll
    for (int j = 0; j < K_; j++) { bufd[j][t] = key[j]; bufi[j][t] = id[j]; }

    // tree merge: 8 lists -> 4 -> 2 -> 1 (partner waves at stride step*64)
    int* op = idxOut + ((size_t)b * N_ + q) * K_;
    for (int step = 1; step < S_; step <<= 1) {
        bool active = (w & (2 * step - 1)) == 0;
        float md[K_];
        int   mi[K_];
        __syncthreads();
        if (active) {
            int pa = t, pb = t + step * 64;
            int ia = 0, ib = 0;
#pragma unroll
            for (int r = 0; r < K_; ++r) {
                float ka = bufd[ia][pa];
                float kb = bufd[ib][pb];
                bool sel = ka <= kb;
                md[r] = sel ? ka : kb;
                mi[r] = sel ? bufi[ia][pa] : bufi[ib][pb];
                ia += sel ? 1 : 0;
                ib += sel ? 0 : 1;
            }
        }
        __syncthreads();
        if (active) {
            if (step == S_ / 2) {
#pragma unroll
                for (int r = 0; r < K_; ++r) op[r] = mi[r];
            } else {
#pragma unroll
                for (int r = 0; r < K_; ++r) { bufd[r][t] = md[r]; bufi[r][t] = mi[r]; }
            }
        }
    }
}

// ---------------- gather 16 neighbor rows of feats, mean ----------------
__global__ __launch_bounds__(256) void gather_mean(const float* __restrict__ feats,
                                                   const int* __restrict__ idx,
                                                   float* __restrict__ x0) {
    int t = blockIdx.x * 256 + threadIdx.x;   // over BN_*64
    int row = t >> 6;
    int c = t & 63;
    int b = row >> 13;                        // N_=8192
    const float* fb = feats + ((size_t)b * N_) * 64;
    const int* ip = idx + (size_t)row * K_;
    float acc = 0.0f;
#pragma unroll
    for (int j = 0; j < K_; j++) acc += fb[(size_t)ip[j] * 64 + c];
    x0[(size_t)row * 64 + c] = acc * (1.0f / 16.0f);
}

// ---------------- stage 1: y1 = x0 @ W1 + b1 ----------------
__global__ __launch_bounds__(256) void mm1_kernel(const float* __restrict__ X,
                                                  const float* __restrict__ W,
                                                  const float* __restrict__ bias,
                                                  float* __restrict__ Y) {
    __shared__ float Ws[64 * 64];
    for (int i = threadIdx.x; i < 64 * 64; i += 256) Ws[i] = W[i];
    __syncthreads();
    size_t r = (size_t)blockIdx.x * 256 + threadIdx.x;
    float x[64];
    const float4* xp = (const float4*)(X + r * 64);
#pragma unroll
    for (int i = 0; i < 16; i++) {
        float4 v = xp[i];
        x[4 * i] = v.x; x[4 * i + 1] = v.y; x[4 * i + 2] = v.z; x[4 * i + 3] = v.w;
    }
    float acc[64];
#pragma unroll
    for (int j = 0; j < 64; j++) acc[j] = bias[j];
#pragma unroll
    for (int c = 0; c < 64; c++) {
        float xv = x[c];
#pragma unroll
        for (int j = 0; j < 64; j++) acc[j] = fmaf(xv, Ws[c * 64 + j], acc[j]);
    }
    float4* yp = (float4*)(Y + r * 64);
#pragma unroll
    for (int i = 0; i < 16; i++)
        yp[i] = make_float4(acc[4 * i], acc[4 * i + 1], acc[4 * i + 2], acc[4 * i + 3]);
}

// ---------------- per-channel sum/sumsq partials (deterministic) ----------------
template <int C>
__global__ __launch_bounds__(256) void stat_partial(const float* __restrict__ Y,
                                                    float* __restrict__ part) {
    const int RP = 256 / C;
    int c = threadIdx.x & (C - 1);
    int rs = threadIdx.x / C;
    float s1 = 0.0f, s2 = 0.0f;
    for (int r = blockIdx.x * RP + rs; r < BN_; r += gridDim.x * RP) {
        float v = Y[(size_t)r * C + c];
        s1 += v;
        s2 = fmaf(v, v, s2);
    }
    __shared__ float l1[256], l2[256];
    l1[threadIdx.x] = s1; l2[threadIdx.x] = s2;
    __syncthreads();
    if (threadIdx.x < C) {
#pragma unroll
        for (int k = 1; k < RP; k++) { s1 += l1[threadIdx.x + k * C]; s2 += l2[threadIdx.x + k * C]; }
        part[(size_t)blockIdx.x * 2 * C + c] = s1;
        part[(size_t)blockIdx.x * 2 * C + C + c] = s2;
    }
}

template <int C>
__global__ void stat_reduce(const float* __restrict__ part, int G, float* __restrict__ stats) {
    int c = threadIdx.x;
    if (c >= C) return;
    float s1 = 0.0f, s2 = 0.0f;
    for (int g = 0; g < G; g++) { s1 += part[(size_t)g * 2 * C + c]; s2 += part[(size_t)g * 2 * C + C + c]; }
    float mean = s1 / (float)BN_;
    float var = s2 / (float)BN_ - mean * mean;
    stats[c] = mean;
    stats[C + c] = rsqrtf(var + EPS_);
}

// ---------------- stage 2: x1 = relu(bn1(y1)); y2 = x1 @ Wa + ba ----------------
__global__ __launch_bounds__(256) void mm2_kernel(const float* __restrict__ Y1,
                                                  const float* __restrict__ Wa,
                                                  const float* __restrict__ ba,
                                                  const float* __restrict__ g1,
                                                  const float* __restrict__ be1,
                                                  const float* __restrict__ stats1,
                                                  float* __restrict__ X1,
                                                  float* __restrict__ Y2) {
    __shared__ float Ws[64 * 64];
    __shared__ float sc[64], sh[64];
    for (int i = threadIdx.x; i < 64 * 64; i += 256) Ws[i] = Wa[i];
    if (threadIdx.x < 64) {
        int c = threadIdx.x;
        float m = stats1[c], rs = stats1[64 + c];
        float scale = rs * g1[c];
        sc[c] = scale;
        sh[c] = be1[c] - m * scale;
    }
    __syncthreads();
    size_t r = (size_t)blockIdx.x * 256 + threadIdx.x;
    float x[64];
    const float4* xp = (const float4*)(Y1 + r * 64);
#pragma unroll
    for (int i = 0; i < 16; i++) {
        float4 v = xp[i];
        x[4 * i]     = fmaxf(0.0f, fmaf(v.x, sc[4 * i],     sh[4 * i]));
        x[4 * i + 1] = fmaxf(0.0f, fmaf(v.y, sc[4 * i + 1], sh[4 * i + 1]));
        x[4 * i + 2] = fmaxf(0.0f, fmaf(v.z, sc[4 * i + 2], sh[4 * i + 2]));
        x[4 * i + 3] = fmaxf(0.0f, fmaf(v.w, sc[4 * i + 3], sh[4 * i + 3]));
    }
    float4* x1p = (float4*)(X1 + r * 64);
#pragma unroll
    for (int i = 0; i < 16; i++)
        x1p[i] = make_float4(x[4 * i], x[4 * i + 1], x[4 * i + 2], x[4 * i + 3]);
    float acc[64];
#pragma unroll
    for (int j = 0; j < 64; j++) acc[j] = ba[j];
#pragma unroll
    for (int c = 0; c < 64; c++) {
        float xv = x[c];
#pragma unroll
        for (int j = 0; j < 64; j++) acc[j] = fmaf(xv, Ws[c * 64 + j], acc[j]);
    }
    float4* yp = (float4*)(Y2 + r * 64);
#pragma unroll
    for (int i = 0; i < 16; i++)
        yp[i] = make_float4(acc[4 * i], acc[4 * i + 1], acc[4 * i + 2], acc[4 * i + 3]);
}

// ---------------- stage 3: attn = sigmoid(relu(bn2(y2))); fused = x1*(1+attn); y3 = fused @ W2 + b2 ----------------
__global__ __launch_bounds__(256) void mm3_kernel(const float* __restrict__ Y2,
                                                  const float* __restrict__ X1,
                                                  const float* __restrict__ W2,
                                                  const float* __restrict__ b2,
                                                  const float* __restrict__ ga,
                                                  const float* __restrict__ bea,
                                                  const float* __restrict__ stats2,
                                                  float* __restrict__ Y3) {
    __shared__ float Ws[64 * 128];
    __shared__ float sc[64], sh[64];
    for (int i = threadIdx.x; i < 64 * 128; i += 256) Ws[i] = W2[i];
    if (threadIdx.x < 64) {
        int c = threadIdx.x;
        float m = stats2[c], rs = stats2[64 + c];
        float scale = rs * ga[c];
        sc[c] = scale;
        sh[c] = bea[c] - m * scale;
    }
    __syncthreads();
    size_t r = (size_t)blockIdx.x * 256 + threadIdx.x;
    float fx[64];
    const float4* y2p = (const float4*)(Y2 + r * 64);
    const float4* x1p = (const float4*)(X1 + r * 64);
#pragma unroll
    for (int i = 0; i < 16; i++) {
        float4 v = y2p[i];
        float4 u = x1p[i];
        float t0 = fmaxf(0.0f, fmaf(v.x, sc[4 * i],     sh[4 * i]));
        float t1 = fmaxf(0.0f, fmaf(v.y, sc[4 * i + 1], sh[4 * i + 1]));
        float t2 = fmaxf(0.0f, fmaf(v.z, sc[4 * i + 2], sh[4 * i + 2]));
        float t3 = fmaxf(0.0f, fmaf(v.w, sc[4 * i + 3], sh[4 * i + 3]));
        float a0 = 1.0f / (1.0f + __expf(-t0));
        float a1 = 1.0f / (1.0f + __expf(-t1));
        float a2 = 1.0f / (1.0f + __expf(-t2));
        float a3 = 1.0f / (1.0f + __expf(-t3));
        fx[4 * i]     = u.x * (1.0f + a0);
        fx[4 * i + 1] = u.y * (1.0f + a1);
        fx[4 * i + 2] = u.z * (1.0f + a2);
        fx[4 * i + 3] = u.w * (1.0f + a3);
    }
    float acc[64];
#pragma unroll 1
    for (int h = 0; h < 2; ++h) {
#pragma unroll
        for (int j = 0; j < 64; j++) acc[j] = b2[h * 64 + j];
#pragma unroll
        for (int c = 0; c < 64; c++) {
            float xv = fx[c];
#pragma unroll
            for (int j = 0; j < 64; j++) acc[j] = fmaf(xv, Ws[c * 128 + h * 64 + j], acc[j]);
        }
        float4* yp = (float4*)(Y3 + r * 128 + h * 64);
#pragma unroll
        for (int i = 0; i < 16; i++)
            yp[i] = make_float4(acc[4 * i], acc[4 * i + 1], acc[4 * i + 2], acc[4 * i + 3]);
    }
}

// ---------------- final: out = relu(bn3(y3)) in-place ----------------
__global__ __launch_bounds__(256) void bn_final(float* __restrict__ Y3,
                                                const float* __restrict__ g2,
                                                const float* __restrict__ be2,
                                                const float* __restrict__ stats3) {
    __shared__ float sc[128], sh[128];
    if (threadIdx.x < 128) {
        int c = threadIdx.x;
        float m = stats3[c], rs = stats3[128 + c];
        float s = rs * g2[c];
        sc[c] = s;
        sh[c] = be2[c] - m * s;
    }
    __syncthreads();
    size_t i = (size_t)blockIdx.x * 256 + threadIdx.x;   // over BN_*128/4 float4s
    float4* p = (float4*)Y3;
    float4 v = p[i];
    int c0 = (int)((i * 4) & 127);
    v.x = fmaxf(0.0f, fmaf(v.x, sc[c0],     sh[c0]));
    v.y = fmaxf(0.0f, fmaf(v.y, sc[c0 + 1], sh[c0 + 1]));
    v.z = fmaxf(0.0f, fmaf(v.z, sc[c0 + 2], sh[c0 + 2]));
    v.w = fmaxf(0.0f, fmaf(v.w, sc[c0 + 3], sh[c0 + 3]));
    p[i] = v;
}

extern "C" void kernel_launch(void* const* d_in, const int* in_sizes, int n_in,
                              void* d_out, int out_size, void* d_ws, size_t ws_size,
                              hipStream_t stream) {
    const float* coords = (const float*)d_in[0];
    const float* feats  = (const float*)d_in[1];
    const float* W1  = (const float*)d_in[3];
    const float* b1  = (const float*)d_in[4];
    const float* g1  = (const float*)d_in[5];
    const float* be1 = (const float*)d_in[6];
    const float* Wa  = (const float*)d_in[7];
    const float* ba  = (const float*)d_in[8];
    const float* ga  = (const float*)d_in[9];
    const float* bea = (const float*)d_in[10];
    const float* W2  = (const float*)d_in[11];
    const float* b2  = (const float*)d_in[12];
    const float* g2  = (const float*)d_in[13];
    const float* be2 = (const float*)d_in[14];

    float* ws = (float*)d_ws;
    float4* coords4 = (float4*)ws;                         // BN_ float4 = 131072 floats
    int*    idxbuf  = (int*)(ws + 131072);                 // BN_*16 ints = 524288 slots
    float*  x0 = ws + 131072 + 524288;                     // BN_*64
    float*  y1 = x0 + (size_t)BN_ * 64;
    float*  x1 = y1 + (size_t)BN_ * 64;
    float*  y2 = x1 + (size_t)BN_ * 64;
    float*  part   = y2 + (size_t)BN_ * 64;                // 256 * 256 floats
    float*  stats1 = part + 256 * 256;                     // 128
    float*  stats2 = stats1 + 128;                         // 128
    float*  stats3 = stats2 + 128;                         // 256
    float*  y3 = (float*)d_out;                            // BN_*128 lives in d_out

    pack_coords<<<(BN_ + 255) / 256, 256, 0, stream>>>(coords, coords4);
    knn_kernel<<<B_ * (N_ / QPB), TPB, 0, stream>>>(coords4, idxbuf);
    gather_mean<<<BN_ * 64 / 256, 256, 0, stream>>>(feats, idxbuf, x0);

    mm1_kernel<<<BN_ / 256, 256, 0, stream>>>(x0, W1, b1, y1);
    stat_partial<64><<<256, 256, 0, stream>>>(y1, part);
    stat_reduce<64><<<1, 64, 0, stream>>>(part, 256, stats1);

    mm2_kernel<<<BN_ / 256, 256, 0, stream>>>(y1, Wa, ba, g1, be1, stats1, x1, y2);
    stat_partial<64><<<256, 256, 0, stream>>>(y2, part);
    stat_reduce<64><<<1, 64, 0, stream>>>(part, 256, stats2);

    mm3_kernel<<<BN_ / 256, 256, 0, stream>>>(y2, x1, W2, b2, ga, bea, stats2, y3);
    stat_partial<128><<<256, 256, 0, stream>>>(y3, part);
    stat_reduce<128><<<1, 128, 0, stream>>>(part, 256, stats3);

    bn_final<<<(size_t)BN_ * 128 / 4 / 256, 256, 0, stream>>>(y3, g2, be2, stats3);
}

// Round 4
// 468.372 us; speedup vs baseline: 2.5602x; 1.3809x over previous
//
#include <hip/hip_runtime.h>
#include <hip/hip_bf16.h>
#include <math.h>

#define B_ 4
#define N_ 8192
#define K_ 16
#define BN_ (B_ * N_)
#define EPS_ 1e-5f

#define S_ 8              // candidate splits = waves per block
#define TPB (S_ * 64)     // 512 threads
#define QPB 64            // queries per block (one per lane)
#define MCAND (N_ / S_)   // 1024 candidates per wave
#define DEPTH 16          // deferred-insert buffer depth per lane

// ---------------- pack coords (B*N,3) -> float4 ----------------
__global__ __launch_bounds__(256) void pack_coords(const float* __restrict__ coords,
                                                   float4* __restrict__ out) {
    int i = blockIdx.x * 256 + threadIdx.x;
    if (i >= BN_) return;
    out[i] = make_float4(coords[3 * i], coords[3 * i + 1], coords[3 * i + 2], 0.0f);
}

// ---------------- exact 16-NN: scalar-broadcast candidates, deferred insertion ----------------
// One query per lane; wave w scans contiguous candidate range with wave-uniform
// addresses (s_load broadcast). Passing candidates push a packed (d2,idx) float2
// into a per-lane LDS column; 16-deep register insertion runs only on flushes.
// 8 sorted lists per query merged via 3-round LDS tree merge.
__global__ __launch_bounds__(512) void knn_kernel(const float4* __restrict__ coords4,
                                                  int* __restrict__ idxOut) {
    __shared__ float2 bufp[DEPTH][TPB];       // 64 KB

    const int bpb = N_ / QPB;                 // 128 blocks per batch
    int b = blockIdx.x / bpb;
    int qbase = (blockIdx.x % bpb) * QPB;
    int t = threadIdx.x;
    int lane = t & 63;
    int w = __builtin_amdgcn_readfirstlane(t >> 6);   // wave-uniform split id -> SGPR
    int q = qbase + lane;

    const float4* cb = coords4 + (size_t)b * N_;
    float4 qc = cb[q];
    float qx = qc.x, qy = qc.y, qz = qc.z;

    float key[K_];
    int   id[K_];
#pragma unroll
    for (int j = 0; j < K_; j++) { key[j] = 3.4e38f; id[j] = -1; }

    int cnt = 0;

    auto flush = [&]() {
        for (int j = 0; j < cnt; ++j) {
            float2 e = bufp[j][t];
            float d2 = e.x;
            int   m  = __float_as_int(e.y);
            if (d2 < key[K_ - 1]) {
#pragma unroll
                for (int jj = K_ - 1; jj > 0; --jj) {
                    bool up = d2 < key[jj - 1];
                    float ik = fminf(d2, key[jj]);
                    int   ii = (d2 < key[jj]) ? m : id[jj];
                    key[jj] = up ? key[jj - 1] : ik;
                    id[jj]  = up ? id[jj - 1]  : ii;
                }
                if (d2 < key[0]) { key[0] = d2; id[0] = m; }
            }
        }
        cnt = 0;
    };

    auto proc = [&](float4 c, int m) {
        float dx = qx - c.x, dy = qy - c.y, dz = qz - c.z;
        float d2 = dx * dx;
        d2 = fmaf(dy, dy, d2);
        d2 = fmaf(dz, dz, d2);
        if (d2 < key[K_ - 1]) {
            bufp[cnt][t] = make_float2(d2, __int_as_float(m));
            cnt++;
        }
    };

    const int base = w * MCAND;
    for (int i = 0; i < MCAND; i += 8) {
        // wave-uniform addresses -> scalar loads (SMEM broadcast)
        float4 c0 = cb[base + i + 0];
        float4 c1 = cb[base + i + 1];
        float4 c2 = cb[base + i + 2];
        float4 c3 = cb[base + i + 3];
        float4 c4 = cb[base + i + 4];
        float4 c5 = cb[base + i + 5];
        float4 c6 = cb[base + i + 6];
        float4 c7 = cb[base + i + 7];
        proc(c0, base + i + 0);
        proc(c1, base + i + 1);
        proc(c2, base + i + 2);
        proc(c3, base + i + 3);
        proc(c4, base + i + 4);
        proc(c5, base + i + 5);
        proc(c6, base + i + 6);
        proc(c7, base + i + 7);
        // each lane pushed at most 8 since last check; DEPTH-7 guard => no overflow
        if (__any(cnt >= DEPTH - 7)) flush();
    }
    flush();

    // publish this lane's sorted 16-list into its LDS column
#pragma unroll
    for (int j = 0; j < K_; j++) bufp[j][t] = make_float2(key[j], __int_as_float(id[j]));

    // tree merge: 8 lists -> 4 -> 2 -> 1 (partner waves at stride step*64)
    int* op = idxOut + ((size_t)b * N_ + q) * K_;
    for (int step = 1; step < S_; step <<= 1) {
        bool active = (w & (2 * step - 1)) == 0;
        float md[K_];
        int   mi[K_];
        __syncthreads();
        if (active) {
            int pa = t, pb = t + step * 64;
            int ia = 0, ib = 0;
#pragma unroll
            for (int r = 0; r < K_; ++r) {
                float2 ea = bufp[ia][pa];
                float2 eb = bufp[ib][pb];
                bool sel = ea.x <= eb.x;
                md[r] = sel ? ea.x : eb.x;
                mi[r] = __float_as_int(sel ? ea.y : eb.y);
                ia += sel ? 1 : 0;
                ib += sel ? 0 : 1;
            }
        }
        __syncthreads();
        if (active) {
            if (step == S_ / 2) {
#pragma unroll
                for (int r = 0; r < K_; ++r) op[r] = mi[r];
            } else {
#pragma unroll
                for (int r = 0; r < K_; ++r) bufp[r][t] = make_float2(md[r], __int_as_float(mi[r]));
            }
        }
    }
}

// ---------------- gather 16 neighbor rows of feats, mean ----------------
__global__ __launch_bounds__(256) void gather_mean(const float* __restrict__ feats,
                                                   const int* __restrict__ idx,
                                                   float* __restrict__ x0) {
    int t = blockIdx.x * 256 + threadIdx.x;   // over BN_*64
    int row = t >> 6;
    int c = t & 63;
    int b = row >> 13;                        // N_=8192
    const float* fb = feats + ((size_t)b * N_) * 64;
    const int* ip = idx + (size_t)row * K_;
    float acc = 0.0f;
#pragma unroll
    for (int j = 0; j < K_; j++) acc += fb[(size_t)ip[j] * 64 + c];
    x0[(size_t)row * 64 + c] = acc * (1.0f / 16.0f);
}

// ---------------- stage 1: y1 = x0 @ W1 + b1 ----------------
__global__ __launch_bounds__(256) void mm1_kernel(const float* __restrict__ X,
                                                  const float* __restrict__ W,
                                                  const float* __restrict__ bias,
                                                  float* __restrict__ Y) {
    __shared__ float Ws[64 * 64];
    for (int i = threadIdx.x; i < 64 * 64; i += 256) Ws[i] = W[i];
    __syncthreads();
    size_t r = (size_t)blockIdx.x * 256 + threadIdx.x;
    float x[64];
    const float4* xp = (const float4*)(X + r * 64);
#pragma unroll
    for (int i = 0; i < 16; i++) {
        float4 v = xp[i];
        x[4 * i] = v.x; x[4 * i + 1] = v.y; x[4 * i + 2] = v.z; x[4 * i + 3] = v.w;
    }
    float acc[64];
#pragma unroll
    for (int j = 0; j < 64; j++) acc[j] = bias[j];
#pragma unroll
    for (int c = 0; c < 64; c++) {
        float xv = x[c];
#pragma unroll
        for (int jj = 0; jj < 16; jj++) {
            float4 w4 = *(const float4*)&Ws[c * 64 + 4 * jj];
            acc[4 * jj]     = fmaf(xv, w4.x, acc[4 * jj]);
            acc[4 * jj + 1] = fmaf(xv, w4.y, acc[4 * jj + 1]);
            acc[4 * jj + 2] = fmaf(xv, w4.z, acc[4 * jj + 2]);
            acc[4 * jj + 3] = fmaf(xv, w4.w, acc[4 * jj + 3]);
        }
    }
    float4* yp = (float4*)(Y + r * 64);
#pragma unroll
    for (int i = 0; i < 16; i++)
        yp[i] = make_float4(acc[4 * i], acc[4 * i + 1], acc[4 * i + 2], acc[4 * i + 3]);
}

// ---------------- per-channel sum/sumsq partials (deterministic) ----------------
template <int C>
__global__ __launch_bounds__(256) void stat_partial(const float* __restrict__ Y,
                                                    float* __restrict__ part) {
    const int RP = 256 / C;
    int c = threadIdx.x & (C - 1);
    int rs = threadIdx.x / C;
    float s1 = 0.0f, s2 = 0.0f;
    for (int r = blockIdx.x * RP + rs; r < BN_; r += gridDim.x * RP) {
        float v = Y[(size_t)r * C + c];
        s1 += v;
        s2 = fmaf(v, v, s2);
    }
    __shared__ float l1[256], l2[256];
    l1[threadIdx.x] = s1; l2[threadIdx.x] = s2;
    __syncthreads();
    if (threadIdx.x < C) {
#pragma unroll
        for (int k = 1; k < RP; k++) { s1 += l1[threadIdx.x + k * C]; s2 += l2[threadIdx.x + k * C]; }
        part[(size_t)blockIdx.x * 2 * C + c] = s1;
        part[(size_t)blockIdx.x * 2 * C + C + c] = s2;
    }
}

// ---------------- stage 2: x1 = relu(bn1(y1)); y2 = x1 @ Wa + ba ----------------
// stats1 computed in-block from the 256-group partials (deterministic fixed order)
__global__ __launch_bounds__(256) void mm2_kernel(const float* __restrict__ Y1,
                                                  const float* __restrict__ Wa,
                                                  const float* __restrict__ ba,
                                                  const float* __restrict__ g1,
                                                  const float* __restrict__ be1,
                                                  const float* __restrict__ part,
                                                  float* __restrict__ X1,
                                                  float* __restrict__ Y2) {
    __shared__ float Ws[64 * 64];
    __shared__ float red[256];
    __shared__ float sc[64], sh[64];
    int t = threadIdx.x;
    for (int i = t; i < 64 * 64; i += 256) Ws[i] = Wa[i];
    {
        int col = t & 127;
        int half = t >> 7;
        float s = 0.0f;
#pragma unroll 8
        for (int g = half * 128; g < half * 128 + 128; ++g) s += part[(size_t)g * 128 + col];
        red[t] = s;
    }
    __syncthreads();
    if (t < 64) {
        float s1 = red[t] + red[t + 128];
        float s2 = red[t + 64] + red[t + 192];
        float mean = s1 * (1.0f / BN_);
        float var = s2 * (1.0f / BN_) - mean * mean;
        float rstd = rsqrtf(var + EPS_);
        float scl = rstd * g1[t];
        sc[t] = scl;
        sh[t] = be1[t] - mean * scl;
    }
    __syncthreads();
    size_t r = (size_t)blockIdx.x * 256 + t;
    float x[64];
    const float4* xp = (const float4*)(Y1 + r * 64);
#pragma unroll
    for (int i = 0; i < 16; i++) {
        float4 v = xp[i];
        x[4 * i]     = fmaxf(0.0f, fmaf(v.x, sc[4 * i],     sh[4 * i]));
        x[4 * i + 1] = fmaxf(0.0f, fmaf(v.y, sc[4 * i + 1], sh[4 * i + 1]));
        x[4 * i + 2] = fmaxf(0.0f, fmaf(v.z, sc[4 * i + 2], sh[4 * i + 2]));
        x[4 * i + 3] = fmaxf(0.0f, fmaf(v.w, sc[4 * i + 3], sh[4 * i + 3]));
    }
    float4* x1p = (float4*)(X1 + r * 64);
#pragma unroll
    for (int i = 0; i < 16; i++)
        x1p[i] = make_float4(x[4 * i], x[4 * i + 1], x[4 * i + 2], x[4 * i + 3]);
    float acc[64];
#pragma unroll
    for (int j = 0; j < 64; j++) acc[j] = ba[j];
#pragma unroll
    for (int c = 0; c < 64; c++) {
        float xv = x[c];
#pragma unroll
        for (int jj = 0; jj < 16; jj++) {
            float4 w4 = *(const float4*)&Ws[c * 64 + 4 * jj];
            acc[4 * jj]     = fmaf(xv, w4.x, acc[4 * jj]);
            acc[4 * jj + 1] = fmaf(xv, w4.y, acc[4 * jj + 1]);
            acc[4 * jj + 2] = fmaf(xv, w4.z, acc[4 * jj + 2]);
            acc[4 * jj + 3] = fmaf(xv, w4.w, acc[4 * jj + 3]);
        }
    }
    float4* yp = (float4*)(Y2 + r * 64);
#pragma unroll
    for (int i = 0; i < 16; i++)
        yp[i] = make_float4(acc[4 * i], acc[4 * i + 1], acc[4 * i + 2], acc[4 * i + 3]);
}

// ---------------- stage 3: attn = sigmoid(relu(bn2(y2))); fused = x1*(1+attn); y3 = fused @ W2 + b2 ----------------
__global__ __launch_bounds__(256) void mm3_kernel(const float* __restrict__ Y2,
                                                  const float* __restrict__ X1,
                                                  const float* __restrict__ W2,
                                                  const float* __restrict__ b2,
                                                  const float* __restrict__ ga,
                                                  const float* __restrict__ bea,
                                                  const float* __restrict__ part,
                                                  float* __restrict__ Y3) {
    __shared__ float Ws[64 * 128];
    __shared__ float red[256];
    __shared__ float sc[64], sh[64];
    int t = threadIdx.x;
    for (int i = t; i < 64 * 128; i += 256) Ws[i] = W2[i];
    {
        int col = t & 127;
        int half = t >> 7;
        float s = 0.0f;
#pragma unroll 8
        for (int g = half * 128; g < half * 128 + 128; ++g) s += part[(size_t)g * 128 + col];
        red[t] = s;
    }
    __syncthreads();
    if (t < 64) {
        float s1 = red[t] + red[t + 128];
        float s2 = red[t + 64] + red[t + 192];
        float mean = s1 * (1.0f / BN_);
        float var = s2 * (1.0f / BN_) - mean * mean;
        float rstd = rsqrtf(var + EPS_);
        float scl = rstd * ga[t];
        sc[t] = scl;
        sh[t] = bea[t] - mean * scl;
    }
    __syncthreads();
    size_t r = (size_t)blockIdx.x * 256 + t;
    float fx[64];
    const float4* y2p = (const float4*)(Y2 + r * 64);
    const float4* x1p = (const float4*)(X1 + r * 64);
#pragma unroll
    for (int i = 0; i < 16; i++) {
        float4 v = y2p[i];
        float4 u = x1p[i];
        float t0 = fmaxf(0.0f, fmaf(v.x, sc[4 * i],     sh[4 * i]));
        float t1 = fmaxf(0.0f, fmaf(v.y, sc[4 * i + 1], sh[4 * i + 1]));
        float t2 = fmaxf(0.0f, fmaf(v.z, sc[4 * i + 2], sh[4 * i + 2]));
        float t3 = fmaxf(0.0f, fmaf(v.w, sc[4 * i + 3], sh[4 * i + 3]));
        float a0 = 1.0f / (1.0f + __expf(-t0));
        float a1 = 1.0f / (1.0f + __expf(-t1));
        float a2 = 1.0f / (1.0f + __expf(-t2));
        float a3 = 1.0f / (1.0f + __expf(-t3));
        fx[4 * i]     = u.x * (1.0f + a0);
        fx[4 * i + 1] = u.y * (1.0f + a1);
        fx[4 * i + 2] = u.z * (1.0f + a2);
        fx[4 * i + 3] = u.w * (1.0f + a3);
    }
    float acc[64];
#pragma unroll 1
    for (int h = 0; h < 2; ++h) {
#pragma unroll
        for (int j = 0; j < 64; j++) acc[j] = b2[h * 64 + j];
#pragma unroll
        for (int c = 0; c < 64; c++) {
            float xv = fx[c];
#pragma unroll
            for (int jj = 0; jj < 16; jj++) {
                float4 w4 = *(const float4*)&Ws[c * 128 + h * 64 + 4 * jj];
                acc[4 * jj]     = fmaf(xv, w4.x, acc[4 * jj]);
                acc[4 * jj + 1] = fmaf(xv, w4.y, acc[4 * jj + 1]);
                acc[4 * jj + 2] = fmaf(xv, w4.z, acc[4 * jj + 2]);
                acc[4 * jj + 3] = fmaf(xv, w4.w, acc[4 * jj + 3]);
            }
        }
        float4* yp = (float4*)(Y3 + r * 128 + h * 64);
#pragma unroll
        for (int i = 0; i < 16; i++)
            yp[i] = make_float4(acc[4 * i], acc[4 * i + 1], acc[4 * i + 2], acc[4 * i + 3]);
    }
}

// ---------------- final: out = relu(bn3(y3)) in-place, grid-stride ----------------
__global__ __launch_bounds__(256) void bn_final(float* __restrict__ Y3,
                                                const float* __restrict__ g2,
                                                const float* __restrict__ be2,
                                                const float* __restrict__ part) {
    __shared__ float red[256];
    __shared__ float sc[128], sh[128];
    int t = threadIdx.x;
    {
        float s = 0.0f;
#pragma unroll 8
        for (int g = 0; g < 256; ++g) s += part[(size_t)g * 256 + t];
        red[t] = s;
    }
    __syncthreads();
    if (t < 128) {
        float mean = red[t] * (1.0f / BN_);
        float var = red[t + 128] * (1.0f / BN_) - mean * mean;
        float rstd = rsqrtf(var + EPS_);
        float scl = rstd * g2[t];
        sc[t] = scl;
        sh[t] = be2[t] - mean * scl;
    }
    __syncthreads();
    const int total = BN_ * 128 / 4;
    float4* p = (float4*)Y3;
    for (int i = blockIdx.x * 256 + t; i < total; i += 256 * 256) {
        float4 v = p[i];
        int c0 = (i * 4) & 127;
        v.x = fmaxf(0.0f, fmaf(v.x, sc[c0],     sh[c0]));
        v.y = fmaxf(0.0f, fmaf(v.y, sc[c0 + 1], sh[c0 + 1]));
        v.z = fmaxf(0.0f, fmaf(v.z, sc[c0 + 2], sh[c0 + 2]));
        v.w = fmaxf(0.0f, fmaf(v.w, sc[c0 + 3], sh[c0 + 3]));
        p[i] = v;
    }
}

extern "C" void kernel_launch(void* const* d_in, const int* in_sizes, int n_in,
                              void* d_out, int out_size, void* d_ws, size_t ws_size,
                              hipStream_t stream) {
    const float* coords = (const float*)d_in[0];
    const float* feats  = (const float*)d_in[1];
    const float* W1  = (const float*)d_in[3];
    const float* b1  = (const float*)d_in[4];
    const float* g1  = (const float*)d_in[5];
    const float* be1 = (const float*)d_in[6];
    const float* Wa  = (const float*)d_in[7];
    const float* ba  = (const float*)d_in[8];
    const float* ga  = (const float*)d_in[9];
    const float* bea = (const float*)d_in[10];
    const float* W2  = (const float*)d_in[11];
    const float* b2  = (const float*)d_in[12];
    const float* g2  = (const float*)d_in[13];
    const float* be2 = (const float*)d_in[14];

    float* ws = (float*)d_ws;
    float4* coords4 = (float4*)ws;                         // BN_ float4 = 131072 floats
    int*    idxbuf  = (int*)(ws + 131072);                 // BN_*16 ints = 524288 slots
    float*  x0 = ws + 131072 + 524288;                     // BN_*64
    float*  y1 = x0 + (size_t)BN_ * 64;
    float*  x1 = y1 + (size_t)BN_ * 64;
    float*  y2 = x1 + (size_t)BN_ * 64;
    float*  part = y2 + (size_t)BN_ * 64;                  // up to 256*256 floats
    float*  y3 = (float*)d_out;                            // BN_*128 lives in d_out

    pack_coords<<<(BN_ + 255) / 256, 256, 0, stream>>>(coords, coords4);
    knn_kernel<<<B_ * (N_ / QPB), TPB, 0, stream>>>(coords4, idxbuf);
    gather_mean<<<BN_ * 64 / 256, 256, 0, stream>>>(feats, idxbuf, x0);

    mm1_kernel<<<BN_ / 256, 256, 0, stream>>>(x0, W1, b1, y1);
    stat_partial<64><<<256, 256, 0, stream>>>(y1, part);

    mm2_kernel<<<BN_ / 256, 256, 0, stream>>>(y1, Wa, ba, g1, be1, part, x1, y2);
    stat_partial<64><<<256, 256, 0, stream>>>(y2, part);

    mm3_kernel<<<BN_ / 256, 256, 0, stream>>>(y2, x1, W2, b2, ga, bea, part, y3);
    stat_partial<128><<<256, 256, 0, stream>>>(y3, part);

    bn_final<<<256, 256, 0, stream>>>(y3, g2, be2, part);
}